// Round 5
// baseline (3153.640 us; speedup 1.0000x reference)
//
#include <hip/hip_runtime.h>
#include <math.h>

#define NN 100000
#define DD 128
#define HH 64
#define KK 8
#define LL 3
#define CC 16
#define EE 1600000
#define NB_SCAN 391  // ceil(NN/256)

// ---------------- CSR build (layer-invariant) ----------------

__global__ __launch_bounds__(256) void deg_kernel(const int* __restrict__ col,
                                                  int* __restrict__ deg) {
  int i = blockIdx.x * 256 + threadIdx.x;  // EE % 256 == 0
  atomicAdd(&deg[col[i]], 1);
}

__global__ __launch_bounds__(256) void dn_kernel(const int* __restrict__ deg,
                                                 float* __restrict__ dn) {
  int i = blockIdx.x * 256 + threadIdx.x;
  if (i < NN) {
    int d = deg[i];
    dn[i] = d > 0 ? 1.0f / sqrtf((float)d) : 0.0f;
  }
}

__global__ __launch_bounds__(256) void scan1_kernel(const int* __restrict__ deg,
                                                    int* __restrict__ offs,
                                                    int* __restrict__ bsum) {
  __shared__ int tmp[256];
  int t = threadIdx.x;
  int i = blockIdx.x * 256 + t;
  int v = (i < NN) ? deg[i] : 0;
  tmp[t] = v;
  __syncthreads();
#pragma unroll
  for (int d = 1; d < 256; d <<= 1) {
    int x = (t >= d) ? tmp[t - d] : 0;
    __syncthreads();
    tmp[t] += x;
    __syncthreads();
  }
  if (i < NN) offs[i] = tmp[t] - v;
  if (t == 255) bsum[blockIdx.x] = tmp[255];
}

__global__ __launch_bounds__(256) void scan2_kernel(int* __restrict__ bsum) {
  __shared__ int tmp[256];
  __shared__ int carry_s;
  int t = threadIdx.x;
  if (t == 0) carry_s = 0;
  __syncthreads();
  for (int base = 0; base < NB_SCAN; base += 256) {
    int i = base + t;
    int v = (i < NB_SCAN) ? bsum[i] : 0;
    tmp[t] = v;
    __syncthreads();
#pragma unroll
    for (int d = 1; d < 256; d <<= 1) {
      int x = (t >= d) ? tmp[t - d] : 0;
      __syncthreads();
      tmp[t] += x;
      __syncthreads();
    }
    int carry = carry_s;
    if (i < NB_SCAN) bsum[i] = carry + tmp[t] - v;
    __syncthreads();
    if (t == 0) carry_s = carry + tmp[255];
    __syncthreads();
  }
}

__global__ __launch_bounds__(256) void scan3_kernel(int* __restrict__ offs,
                                                    const int* __restrict__ bsum) {
  int i = blockIdx.x * 256 + threadIdx.x;
  if (i < NN) offs[i] += bsum[blockIdx.x];
}

__global__ __launch_bounds__(256) void fill_kernel(const int* __restrict__ row,
                                                   const int* __restrict__ col,
                                                   const int* __restrict__ offs,
                                                   int* __restrict__ cursor,
                                                   const float* __restrict__ dn,
                                                   int2* __restrict__ csr) {
  int e = blockIdx.x * 256 + threadIdx.x;  // EE % 256 == 0
  int c = col[e], r = row[e];
  int pos = offs[c] + atomicAdd(&cursor[c], 1);
  int2 p;
  p.x = r;
  p.y = __float_as_int(dn[c] * dn[r]);
  csr[pos] = p;
}

// ---------------- fc0 ----------------

__global__ __launch_bounds__(256) void fc0_kernel(const float* __restrict__ x,
                                                  const float* __restrict__ w,
                                                  const float* __restrict__ b,
                                                  float* __restrict__ h) {
  int id = blockIdx.x * 256 + threadIdx.x;
  int n = id >> 6, o = id & 63;
  const float* xr = x + n * DD;
  float s0 = 0.f, s1 = 0.f, s2 = 0.f, s3 = 0.f;
#pragma unroll
  for (int f = 0; f < DD; f += 4) {
    s0 = fmaf(xr[f + 0], w[(f + 0) * HH + o], s0);
    s1 = fmaf(xr[f + 1], w[(f + 1) * HH + o], s1);
    s2 = fmaf(xr[f + 2], w[(f + 2) * HH + o], s2);
    s3 = fmaf(xr[f + 3], w[(f + 3) * HH + o], s3);
  }
  h[id] = fmaxf((s0 + s1) + (s2 + s3) + b[o], 0.0f);
}

// ---------------- env gate ----------------

__global__ __launch_bounds__(256) void env_kernel(const float* __restrict__ h,
                                                  const float* __restrict__ env_w,
                                                  const float* __restrict__ env_b,
                                                  float* __restrict__ e_out) {
  int n = blockIdx.x * 256 + threadIdx.x;
  if (n >= NN) return;
  float logit[KK];
#pragma unroll
  for (int k = 0; k < KK; ++k) logit[k] = env_b[k];
  const float4* hp = reinterpret_cast<const float4*>(h + n * HH);
#pragma unroll
  for (int f4 = 0; f4 < HH / 4; ++f4) {
    float4 hv = hp[f4];
    float hj[4] = {hv.x, hv.y, hv.z, hv.w};
#pragma unroll
    for (int j = 0; j < 4; ++j) {
      int f = f4 * 4 + j;
#pragma unroll
      for (int k = 0; k < KK; ++k)
        logit[k] = fmaf(hj[j], env_w[f * KK + k], logit[k]);
    }
  }
  float m = logit[0];
#pragma unroll
  for (int k = 1; k < KK; ++k) m = fmaxf(m, logit[k]);
  float p[KK];
  float s = 0.f;
#pragma unroll
  for (int k = 0; k < KK; ++k) {
    p[k] = expf(logit[k] - m);
    s += p[k];
  }
#pragma unroll
  for (int k = 0; k < KK; ++k) {
    float pi = p[k] / s;
    e_out[n * KK + k] = ((double)pi > 0.1) ? pi : 0.0f;
  }
}

// ---------------- GCN gather (CSR, no atomics) ----------------

__global__ __launch_bounds__(256) void gather_kernel(const int2* __restrict__ csr,
                                                     const int* __restrict__ offs,
                                                     const int* __restrict__ deg,
                                                     const float* __restrict__ h,
                                                     float* __restrict__ agg) {
  int n = blockIdx.x * 4 + (threadIdx.x >> 6);
  if (n >= NN) return;
  int lane = threadIdx.x & 63;
  int j = offs[n];
  int end = j + deg[n];
  float a0 = 0.f, a1 = 0.f, a2 = 0.f, a3 = 0.f;
  for (; j + 3 < end; j += 4) {
    int2 p0 = csr[j], p1 = csr[j + 1], p2 = csr[j + 2], p3 = csr[j + 3];
    float h0 = h[p0.x * HH + lane];
    float h1 = h[p1.x * HH + lane];
    float h2 = h[p2.x * HH + lane];
    float h3 = h[p3.x * HH + lane];
    a0 = fmaf(h0, __int_as_float(p0.y), a0);
    a1 = fmaf(h1, __int_as_float(p1.y), a1);
    a2 = fmaf(h2, __int_as_float(p2.y), a2);
    a3 = fmaf(h3, __int_as_float(p3.y), a3);
  }
  for (; j < end; ++j) {
    int2 p = csr[j];
    a0 = fmaf(h[p.x * HH + lane], __int_as_float(p.y), a0);
  }
  agg[n * HH + lane] = (a0 + a1) + (a2 + a3);
}

// ---------------- weight-stationary conv ----------------
// Head-major: for each k, stage w[k]^T in LDS ([o][f], pad 129 -> conflict-free
// ds_read_b128 for lane=o). Each wave owns 16 consecutive nodes (NN%16==0 ->
// wave-uniform liveness); node features stream as wave-uniform scalars
// (s_load path, scalar pipe parallel to VALU). Dense over all 8 heads with the
// e-gate folded as out += e_k * hacc (e==0 annihilates, identical to the
// reference einsum). Inner loop: 1 LDS b128 + 64 FMA -> ~90% FMA.

__global__ __launch_bounds__(256) void conv_kernel(float* __restrict__ h,
                                                   const float* __restrict__ agg,
                                                   const float* __restrict__ eg,
                                                   const float* __restrict__ w) {
  __shared__ float wl[64 * 129];  // 33 KB: w[k] transposed [o][f], pad +1

  int t = threadIdx.x;
  int wv = t >> 6, lane = t & 63;
  int node0 = blockIdx.x * 64 + wv * 16;
  bool live = node0 < NN;          // uniform per wave (NN % 16 == 0)
  int n0 = live ? node0 : 0;

  const float* aggb = agg + (size_t)n0 * HH;  // uniform bases -> scalar loads
  const float* hb   = h + (size_t)n0 * HH;
  const float* eb   = eg + (size_t)n0 * KK;

  float out[16];
#pragma unroll
  for (int i = 0; i < 16; ++i) out[i] = 0.f;

  for (int k = 0; k < KK; ++k) {
    __syncthreads();  // previous k's LDS reads complete
    const float* wk = w + k * (2 * HH * HH);
#pragma unroll
    for (int r = 0; r < 8; ++r) {
      int L = r * 1024 + t * 4;  // linear idx into [128][64]
      int f = L >> 6, o = L & 63;
      float4 v = *reinterpret_cast<const float4*>(wk + L);
      wl[(o + 0) * 129 + f] = v.x;
      wl[(o + 1) * 129 + f] = v.y;
      wl[(o + 2) * 129 + f] = v.z;
      wl[(o + 3) * 129 + f] = v.w;
    }
    __syncthreads();

    float hacc[16];
#pragma unroll
    for (int i = 0; i < 16; ++i) hacc[i] = 0.f;

    const float* wrow = wl + lane * 129;

    // f in [0,64): agg half
#pragma unroll 2
    for (int fq = 0; fq < 16; ++fq) {
      float4 wq = *reinterpret_cast<const float4*>(wrow + fq * 4);
#pragma unroll
      for (int i = 0; i < 16; ++i) {
        float4 hv = *reinterpret_cast<const float4*>(aggb + i * HH + fq * 4);
        hacc[i] = fmaf(wq.x, hv.x, hacc[i]);
        hacc[i] = fmaf(wq.y, hv.y, hacc[i]);
        hacc[i] = fmaf(wq.z, hv.z, hacc[i]);
        hacc[i] = fmaf(wq.w, hv.w, hacc[i]);
      }
    }
    // f in [64,128): h half
#pragma unroll 2
    for (int fq = 0; fq < 16; ++fq) {
      float4 wq = *reinterpret_cast<const float4*>(wrow + 64 + fq * 4);
#pragma unroll
      for (int i = 0; i < 16; ++i) {
        float4 hv = *reinterpret_cast<const float4*>(hb + i * HH + fq * 4);
        hacc[i] = fmaf(wq.x, hv.x, hacc[i]);
        hacc[i] = fmaf(wq.y, hv.y, hacc[i]);
        hacc[i] = fmaf(wq.z, hv.z, hacc[i]);
        hacc[i] = fmaf(wq.w, hv.w, hacc[i]);
      }
    }
    // fold gate (e==0 kills inactive heads)
#pragma unroll
    for (int i = 0; i < 16; ++i)
      out[i] = fmaf(eb[i * KK + k], hacc[i], out[i]);
  }

  // epilogue: h = relu(h + out), in place (this wave is sole reader/writer
  // of its nodes' h rows; all scalar reads of h happened above)
  if (live) {
#pragma unroll
    for (int i = 0; i < 16; ++i) {
      float hv = h[(size_t)(n0 + i) * HH + lane];
      h[(size_t)(n0 + i) * HH + lane] = fmaxf(hv + out[i], 0.0f);
    }
  }
}

// ---------------- fc1 ----------------

__global__ __launch_bounds__(256) void fc1_kernel(const float* __restrict__ h,
                                                  const float* __restrict__ w,
                                                  const float* __restrict__ b,
                                                  float* __restrict__ out) {
  int id = blockIdx.x * 256 + threadIdx.x;
  int n = id >> 4, c = id & 15;
  const float* hr = h + n * HH;
  float acc = b[c];
#pragma unroll
  for (int o = 0; o < HH; ++o) acc = fmaf(hr[o], w[o * CC + c], acc);
  out[id] = acc;
}

// ---------------- launch ----------------

extern "C" void kernel_launch(void* const* d_in, const int* in_sizes, int n_in,
                              void* d_out, int out_size, void* d_ws, size_t ws_size,
                              hipStream_t stream) {
  const float* x      = (const float*)d_in[0];
  const int*   ei     = (const int*)d_in[1];
  const float* fc0_w  = (const float*)d_in[2];
  const float* fc0_b  = (const float*)d_in[3];
  const float* fc1_w  = (const float*)d_in[4];
  const float* fc1_b  = (const float*)d_in[5];
  const float* env_w  = (const float*)d_in[6];
  const float* env_b  = (const float*)d_in[7];
  const float* conv_w = (const float*)d_in[8];
  float* out = (float*)d_out;

  float* ws   = (float*)d_ws;
  float* h    = ws;                        // 6,400,000
  float* agg  = ws + 6400000;              // 6,400,000
  float* e_g  = ws + 12800000;             // 800,000
  float* dn   = ws + 13600000;             // 100,000
  int*   degi = (int*)(ws + 13700000);     // 100,000
  int*   offs = (int*)(ws + 13800000);     // 100,000
  int*   curs = (int*)(ws + 13900000);     // 100,000
  int*   bsum = (int*)(ws + 14000000);     // 1,024
  int2*  csr  = (int2*)(ws + 14002000);    // 1,600,000 * 8B

  const int* row = ei;
  const int* col = ei + EE;

  hipMemsetAsync(degi, 0, NN * sizeof(int), stream);
  hipMemsetAsync(curs, 0, NN * sizeof(int), stream);
  deg_kernel<<<EE / 256, 256, 0, stream>>>(col, degi);
  dn_kernel<<<NB_SCAN, 256, 0, stream>>>(degi, dn);
  scan1_kernel<<<NB_SCAN, 256, 0, stream>>>(degi, offs, bsum);
  scan2_kernel<<<1, 256, 0, stream>>>(bsum);
  scan3_kernel<<<NB_SCAN, 256, 0, stream>>>(offs, bsum);
  fill_kernel<<<EE / 256, 256, 0, stream>>>(row, col, offs, curs, dn, csr);

  fc0_kernel<<<(NN * HH) / 256, 256, 0, stream>>>(x, fc0_w, fc0_b, h);

  for (int l = 0; l < LL; ++l) {
    env_kernel<<<NB_SCAN, 256, 0, stream>>>(
        h, env_w + l * (2 * HH * KK), env_b + l * KK, e_g);
    gather_kernel<<<(NN + 3) / 4, 256, 0, stream>>>(csr, offs, degi, h, agg);
    conv_kernel<<<(NN + 63) / 64, 256, 0, stream>>>(
        h, agg, e_g, conv_w + l * (KK * 2 * HH * HH));
  }

  fc1_kernel<<<(NN * CC) / 256, 256, 0, stream>>>(h, fc1_w, fc1_b, out);
}

// Round 10
// 1874.397 us; speedup vs baseline: 1.6825x; 1.6825x over previous
//
#include <hip/hip_runtime.h>
#include <math.h>

#define NN 100000
#define DD 128
#define HH 64
#define KK 8
#define LL 3
#define CC 16
#define EE 1600000
#define NB_SCAN 391  // ceil(NN/256)

// ---------------- CSR build (layer-invariant) ----------------

__global__ __launch_bounds__(256) void deg_kernel(const int* __restrict__ col,
                                                  int* __restrict__ deg) {
  int i = blockIdx.x * 256 + threadIdx.x;  // EE % 256 == 0
  atomicAdd(&deg[col[i]], 1);
}

__global__ __launch_bounds__(256) void dn_kernel(const int* __restrict__ deg,
                                                 float* __restrict__ dn) {
  int i = blockIdx.x * 256 + threadIdx.x;
  if (i < NN) {
    int d = deg[i];
    dn[i] = d > 0 ? 1.0f / sqrtf((float)d) : 0.0f;
  }
}

__global__ __launch_bounds__(256) void scan1_kernel(const int* __restrict__ deg,
                                                    int* __restrict__ offs,
                                                    int* __restrict__ bsum) {
  __shared__ int tmp[256];
  int t = threadIdx.x;
  int i = blockIdx.x * 256 + t;
  int v = (i < NN) ? deg[i] : 0;
  tmp[t] = v;
  __syncthreads();
#pragma unroll
  for (int d = 1; d < 256; d <<= 1) {
    int x = (t >= d) ? tmp[t - d] : 0;
    __syncthreads();
    tmp[t] += x;
    __syncthreads();
  }
  if (i < NN) offs[i] = tmp[t] - v;
  if (t == 255) bsum[blockIdx.x] = tmp[255];
}

__global__ __launch_bounds__(256) void scan2_kernel(int* __restrict__ bsum) {
  __shared__ int tmp[256];
  __shared__ int carry_s;
  int t = threadIdx.x;
  if (t == 0) carry_s = 0;
  __syncthreads();
  for (int base = 0; base < NB_SCAN; base += 256) {
    int i = base + t;
    int v = (i < NB_SCAN) ? bsum[i] : 0;
    tmp[t] = v;
    __syncthreads();
#pragma unroll
    for (int d = 1; d < 256; d <<= 1) {
      int x = (t >= d) ? tmp[t - d] : 0;
      __syncthreads();
      tmp[t] += x;
      __syncthreads();
    }
    int carry = carry_s;
    if (i < NB_SCAN) bsum[i] = carry + tmp[t] - v;
    __syncthreads();
    if (t == 0) carry_s = carry + tmp[255];
    __syncthreads();
  }
}

__global__ __launch_bounds__(256) void scan3_kernel(int* __restrict__ offs,
                                                    const int* __restrict__ bsum) {
  int i = blockIdx.x * 256 + threadIdx.x;
  if (i < NN) offs[i] += bsum[blockIdx.x];
}

__global__ __launch_bounds__(256) void fill_kernel(const int* __restrict__ row,
                                                   const int* __restrict__ col,
                                                   const int* __restrict__ offs,
                                                   int* __restrict__ cursor,
                                                   const float* __restrict__ dn,
                                                   int2* __restrict__ csr) {
  int e = blockIdx.x * 256 + threadIdx.x;  // EE % 256 == 0
  int c = col[e], r = row[e];
  int pos = offs[c] + atomicAdd(&cursor[c], 1);
  int2 p;
  p.x = r;
  p.y = __float_as_int(dn[c] * dn[r]);
  csr[pos] = p;
}

// ---------------- fc0 ----------------

__global__ __launch_bounds__(256) void fc0_kernel(const float* __restrict__ x,
                                                  const float* __restrict__ w,
                                                  const float* __restrict__ b,
                                                  float* __restrict__ h) {
  int id = blockIdx.x * 256 + threadIdx.x;
  int n = id >> 6, o = id & 63;
  const float* xr = x + n * DD;
  float s0 = 0.f, s1 = 0.f, s2 = 0.f, s3 = 0.f;
#pragma unroll
  for (int f = 0; f < DD; f += 4) {
    s0 = fmaf(xr[f + 0], w[(f + 0) * HH + o], s0);
    s1 = fmaf(xr[f + 1], w[(f + 1) * HH + o], s1);
    s2 = fmaf(xr[f + 2], w[(f + 2) * HH + o], s2);
    s3 = fmaf(xr[f + 3], w[(f + 3) * HH + o], s3);
  }
  h[id] = fmaxf((s0 + s1) + (s2 + s3) + b[o], 0.0f);
}

// ---------------- env gate ----------------

__global__ __launch_bounds__(256) void env_kernel(const float* __restrict__ h,
                                                  const float* __restrict__ env_w,
                                                  const float* __restrict__ env_b,
                                                  float* __restrict__ e_out) {
  int n = blockIdx.x * 256 + threadIdx.x;
  if (n >= NN) return;
  float logit[KK];
#pragma unroll
  for (int k = 0; k < KK; ++k) logit[k] = env_b[k];
  const float4* hp = reinterpret_cast<const float4*>(h + n * HH);
#pragma unroll
  for (int f4 = 0; f4 < HH / 4; ++f4) {
    float4 hv = hp[f4];
    float hj[4] = {hv.x, hv.y, hv.z, hv.w};
#pragma unroll
    for (int j = 0; j < 4; ++j) {
      int f = f4 * 4 + j;
#pragma unroll
      for (int k = 0; k < KK; ++k)
        logit[k] = fmaf(hj[j], env_w[f * KK + k], logit[k]);
    }
  }
  float m = logit[0];
#pragma unroll
  for (int k = 1; k < KK; ++k) m = fmaxf(m, logit[k]);
  float p[KK];
  float s = 0.f;
#pragma unroll
  for (int k = 0; k < KK; ++k) {
    p[k] = expf(logit[k] - m);
    s += p[k];
  }
#pragma unroll
  for (int k = 0; k < KK; ++k) {
    float pi = p[k] / s;
    e_out[n * KK + k] = ((double)pi > 0.1) ? pi : 0.0f;
  }
}

// ---------------- GCN gather (CSR, no atomics) ----------------

__global__ __launch_bounds__(256) void gather_kernel(const int2* __restrict__ csr,
                                                     const int* __restrict__ offs,
                                                     const int* __restrict__ deg,
                                                     const float* __restrict__ h,
                                                     float* __restrict__ agg) {
  int n = blockIdx.x * 4 + (threadIdx.x >> 6);
  if (n >= NN) return;
  int lane = threadIdx.x & 63;
  int j = offs[n];
  int end = j + deg[n];
  float a0 = 0.f, a1 = 0.f, a2 = 0.f, a3 = 0.f;
  for (; j + 3 < end; j += 4) {
    int2 p0 = csr[j], p1 = csr[j + 1], p2 = csr[j + 2], p3 = csr[j + 3];
    float h0 = h[p0.x * HH + lane];
    float h1 = h[p1.x * HH + lane];
    float h2 = h[p2.x * HH + lane];
    float h3 = h[p3.x * HH + lane];
    a0 = fmaf(h0, __int_as_float(p0.y), a0);
    a1 = fmaf(h1, __int_as_float(p1.y), a1);
    a2 = fmaf(h2, __int_as_float(p2.y), a2);
    a3 = fmaf(h3, __int_as_float(p3.y), a3);
  }
  for (; j < end; ++j) {
    int2 p = csr[j];
    a0 = fmaf(h[p.x * HH + lane], __int_as_float(p.y), a0);
  }
  agg[n * HH + lane] = (a0 + a1) + (a2 + a3);
}

// ---------------- conv: o-sliced, LDS-hi, scalar-pipe weights ----------------
// Block = 512 thr = 8 waves = 64 nodes. lane = node; wave wvu owns o-slice
// [wvu*8, wvu*8+8). w indices are wave-uniform (k rolled-loop var, f4 unrolled
// const, wvu via readfirstlane) and w is read-only __restrict__ -> compiler
// emits s_load (scalar pipe, parallel to VALU, zero VMEM/LDS cost).
// hi_s stride 132 floats (= 33*16B): b128-aligned, and lane*132 % 32 = 4*(lane&7)
// -> each 8-lane group tiles all 32 banks exactly once -> conflict-free b128.
// Dense over all 8 heads; gate folded as out += e_k*hacc (e==0 annihilates,
// identical to the reference einsum). e in LDS so the k-loop stays rolled
// (no runtime-indexed VGPR arrays). In-place h write is safe: each block
// reads/writes only its own 64 rows, staged into LDS before the write.

__global__ __launch_bounds__(512) void conv_kernel(float* __restrict__ h,
                                                   const float* __restrict__ agg,
                                                   const float* __restrict__ eg,
                                                   const float* __restrict__ w) {
  __shared__ float hi_s[64 * 132];  // 33.8 KB
  __shared__ float es[64 * 8];      // 2 KB

  int t = threadIdx.x;
  int n0 = blockIdx.x * 64;
  int sn = t >> 3, sc = t & 7;  // staging: node, 16-float chunk

  // stage hi = [agg(0..63) || h(64..127)]; dest f = sc*16
  {
    int n = n0 + sn;
    float* dst = hi_s + sn * 132 + sc * 16;
    if (n < NN) {
      const float* src = (sc < 4) ? (agg + (size_t)n * HH + sc * 16)
                                  : (h + (size_t)n * HH + (sc - 4) * 16);
#pragma unroll
      for (int q = 0; q < 4; ++q)
        reinterpret_cast<float4*>(dst)[q] =
            reinterpret_cast<const float4*>(src)[q];
    } else {
      float4 z = make_float4(0.f, 0.f, 0.f, 0.f);
#pragma unroll
      for (int q = 0; q < 4; ++q) reinterpret_cast<float4*>(dst)[q] = z;
    }
  }
  // stage e (coalesced: thread t -> node t>>3, head t&7)
  {
    int n = n0 + sn;
    es[t] = (n < NN) ? eg[(size_t)n * KK + sc] : 0.f;
  }
  __syncthreads();

  int lane = t & 63;                                      // node within block
  int wvu = __builtin_amdgcn_readfirstlane(t >> 6);       // uniform wave id
  const float* hrow = hi_s + lane * 132;
  const float* wb = w + wvu * 8;  // this wave's o-slice base

  float out[8];
#pragma unroll
  for (int j = 0; j < 8; ++j) out[j] = 0.f;

  for (int k = 0; k < KK; ++k) {  // rolled: body ~10 KB, I-cache safe
    const float* wk = wb + k * (2 * HH * HH);
    float hacc[8];
#pragma unroll
    for (int j = 0; j < 8; ++j) hacc[j] = 0.f;
#pragma unroll
    for (int f4 = 0; f4 < 32; ++f4) {
      float4 hv = *reinterpret_cast<const float4*>(hrow + f4 * 4);
      const float* wf = wk + f4 * 4 * HH;  // uniform -> s_load_dwordx8 x4
#pragma unroll
      for (int j = 0; j < 8; ++j) hacc[j] = fmaf(hv.x, wf[j], hacc[j]);
#pragma unroll
      for (int j = 0; j < 8; ++j) hacc[j] = fmaf(hv.y, wf[HH + j], hacc[j]);
#pragma unroll
      for (int j = 0; j < 8; ++j) hacc[j] = fmaf(hv.z, wf[2 * HH + j], hacc[j]);
#pragma unroll
      for (int j = 0; j < 8; ++j) hacc[j] = fmaf(hv.w, wf[3 * HH + j], hacc[j]);
    }
    float ek = es[lane * 8 + k];
#pragma unroll
    for (int j = 0; j < 8; ++j) out[j] = fmaf(ek, hacc[j], out[j]);
  }

  __syncthreads();  // all waves done reading hi_s
  // res = relu(h + out) into the (now free) agg half of hi_s, for coalescing
#pragma unroll
  for (int j = 0; j < 8; ++j) {
    int o = wvu * 8 + j;
    hi_s[lane * 132 + o] = fmaxf(hrow[64 + o] + out[j], 0.f);
  }
  __syncthreads();
  // coalesced in-place store of this block's 64 rows
  {
    int n = n0 + sn;
    if (n < NN) {
      float* dst = h + (size_t)n * HH + sc * 8;
      const float* srcl = hi_s + sn * 132 + sc * 8;
      reinterpret_cast<float4*>(dst)[0] = reinterpret_cast<const float4*>(srcl)[0];
      reinterpret_cast<float4*>(dst)[1] = reinterpret_cast<const float4*>(srcl)[1];
    }
  }
}

// ---------------- fc1 ----------------

__global__ __launch_bounds__(256) void fc1_kernel(const float* __restrict__ h,
                                                  const float* __restrict__ w,
                                                  const float* __restrict__ b,
                                                  float* __restrict__ out) {
  int id = blockIdx.x * 256 + threadIdx.x;
  int n = id >> 4, c = id & 15;
  const float* hr = h + n * HH;
  float acc = b[c];
#pragma unroll
  for (int o = 0; o < HH; ++o) acc = fmaf(hr[o], w[o * CC + c], acc);
  out[id] = acc;
}

// ---------------- launch ----------------

extern "C" void kernel_launch(void* const* d_in, const int* in_sizes, int n_in,
                              void* d_out, int out_size, void* d_ws, size_t ws_size,
                              hipStream_t stream) {
  const float* x      = (const float*)d_in[0];
  const int*   ei     = (const int*)d_in[1];
  const float* fc0_w  = (const float*)d_in[2];
  const float* fc0_b  = (const float*)d_in[3];
  const float* fc1_w  = (const float*)d_in[4];
  const float* fc1_b  = (const float*)d_in[5];
  const float* env_w  = (const float*)d_in[6];
  const float* env_b  = (const float*)d_in[7];
  const float* conv_w = (const float*)d_in[8];
  float* out = (float*)d_out;

  float* ws   = (float*)d_ws;
  float* h    = ws;                        // 6,400,000
  float* agg  = ws + 6400000;              // 6,400,000
  float* e_g  = ws + 12800000;             // 800,000
  float* dn   = ws + 13600000;             // 100,000
  int*   degi = (int*)(ws + 13700000);     // 100,000
  int*   offs = (int*)(ws + 13800000);     // 100,000
  int*   curs = (int*)(ws + 13900000);     // 100,000
  int*   bsum = (int*)(ws + 14000000);     // 1,024
  int2*  csr  = (int2*)(ws + 14002000);    // 1,600,000 * 8B

  const int* row = ei;
  const int* col = ei + EE;

  hipMemsetAsync(degi, 0, NN * sizeof(int), stream);
  hipMemsetAsync(curs, 0, NN * sizeof(int), stream);
  deg_kernel<<<EE / 256, 256, 0, stream>>>(col, degi);
  dn_kernel<<<NB_SCAN, 256, 0, stream>>>(degi, dn);
  scan1_kernel<<<NB_SCAN, 256, 0, stream>>>(degi, offs, bsum);
  scan2_kernel<<<1, 256, 0, stream>>>(bsum);
  scan3_kernel<<<NB_SCAN, 256, 0, stream>>>(offs, bsum);
  fill_kernel<<<EE / 256, 256, 0, stream>>>(row, col, offs, curs, dn, csr);

  fc0_kernel<<<(NN * HH) / 256, 256, 0, stream>>>(x, fc0_w, fc0_b, h);

  for (int l = 0; l < LL; ++l) {
    env_kernel<<<NB_SCAN, 256, 0, stream>>>(
        h, env_w + l * (2 * HH * KK), env_b + l * KK, e_g);
    gather_kernel<<<(NN + 3) / 4, 256, 0, stream>>>(csr, offs, degi, h, agg);
    conv_kernel<<<(NN + 63) / 64, 512, 0, stream>>>(
        h, agg, e_g, conv_w + l * (KK * 2 * HH * HH));
  }

  fc1_kernel<<<(NN * CC) / 256, 256, 0, stream>>>(h, fc1_w, fc1_b, out);
}

// Round 11
// 1271.361 us; speedup vs baseline: 2.4805x; 1.4743x over previous
//
#include <hip/hip_runtime.h>
#include <math.h>

#define NN 100000
#define DD 128
#define HH 64
#define KK 8
#define LL 3
#define CC 16
#define EE 1600000
#define NB_SCAN 391  // ceil(NN/256)

// ---------------- CSR build (layer-invariant) ----------------

__global__ __launch_bounds__(256) void deg_kernel(const int* __restrict__ col,
                                                  int* __restrict__ deg) {
  int i = blockIdx.x * 256 + threadIdx.x;  // EE % 256 == 0
  atomicAdd(&deg[col[i]], 1);
}

__global__ __launch_bounds__(256) void dn_kernel(const int* __restrict__ deg,
                                                 float* __restrict__ dn) {
  int i = blockIdx.x * 256 + threadIdx.x;
  if (i < NN) {
    int d = deg[i];
    dn[i] = d > 0 ? 1.0f / sqrtf((float)d) : 0.0f;
  }
}

__global__ __launch_bounds__(256) void scan1_kernel(const int* __restrict__ deg,
                                                    int* __restrict__ offs,
                                                    int* __restrict__ bsum) {
  __shared__ int tmp[256];
  int t = threadIdx.x;
  int i = blockIdx.x * 256 + t;
  int v = (i < NN) ? deg[i] : 0;
  tmp[t] = v;
  __syncthreads();
#pragma unroll
  for (int d = 1; d < 256; d <<= 1) {
    int x = (t >= d) ? tmp[t - d] : 0;
    __syncthreads();
    tmp[t] += x;
    __syncthreads();
  }
  if (i < NN) offs[i] = tmp[t] - v;
  if (t == 255) bsum[blockIdx.x] = tmp[255];
}

__global__ __launch_bounds__(256) void scan2_kernel(int* __restrict__ bsum) {
  __shared__ int tmp[256];
  __shared__ int carry_s;
  int t = threadIdx.x;
  if (t == 0) carry_s = 0;
  __syncthreads();
  for (int base = 0; base < NB_SCAN; base += 256) {
    int i = base + t;
    int v = (i < NB_SCAN) ? bsum[i] : 0;
    tmp[t] = v;
    __syncthreads();
#pragma unroll
    for (int d = 1; d < 256; d <<= 1) {
      int x = (t >= d) ? tmp[t - d] : 0;
      __syncthreads();
      tmp[t] += x;
      __syncthreads();
    }
    int carry = carry_s;
    if (i < NB_SCAN) bsum[i] = carry + tmp[t] - v;
    __syncthreads();
    if (t == 0) carry_s = carry + tmp[255];
    __syncthreads();
  }
}

__global__ __launch_bounds__(256) void scan3_kernel(int* __restrict__ offs,
                                                    const int* __restrict__ bsum) {
  int i = blockIdx.x * 256 + threadIdx.x;
  if (i < NN) offs[i] += bsum[blockIdx.x];
}

__global__ __launch_bounds__(256) void fill_kernel(const int* __restrict__ row,
                                                   const int* __restrict__ col,
                                                   const int* __restrict__ offs,
                                                   int* __restrict__ cursor,
                                                   const float* __restrict__ dn,
                                                   int2* __restrict__ csr) {
  int e = blockIdx.x * 256 + threadIdx.x;  // EE % 256 == 0
  int c = col[e], r = row[e];
  int pos = offs[c] + atomicAdd(&cursor[c], 1);
  int2 p;
  p.x = r;
  p.y = __float_as_int(dn[c] * dn[r]);
  csr[pos] = p;
}

// ---------------- fc0 ----------------

__global__ __launch_bounds__(256) void fc0_kernel(const float* __restrict__ x,
                                                  const float* __restrict__ w,
                                                  const float* __restrict__ b,
                                                  float* __restrict__ h) {
  int id = blockIdx.x * 256 + threadIdx.x;
  int n = id >> 6, o = id & 63;
  const float* xr = x + n * DD;
  float s0 = 0.f, s1 = 0.f, s2 = 0.f, s3 = 0.f;
#pragma unroll
  for (int f = 0; f < DD; f += 4) {
    s0 = fmaf(xr[f + 0], w[(f + 0) * HH + o], s0);
    s1 = fmaf(xr[f + 1], w[(f + 1) * HH + o], s1);
    s2 = fmaf(xr[f + 2], w[(f + 2) * HH + o], s2);
    s3 = fmaf(xr[f + 3], w[(f + 3) * HH + o], s3);
  }
  h[id] = fmaxf((s0 + s1) + (s2 + s3) + b[o], 0.0f);
}

// ---------------- env gate ----------------

__global__ __launch_bounds__(256) void env_kernel(const float* __restrict__ h,
                                                  const float* __restrict__ env_w,
                                                  const float* __restrict__ env_b,
                                                  float* __restrict__ e_out) {
  int n = blockIdx.x * 256 + threadIdx.x;
  if (n >= NN) return;
  float logit[KK];
#pragma unroll
  for (int k = 0; k < KK; ++k) logit[k] = env_b[k];
  const float4* hp = reinterpret_cast<const float4*>(h + n * HH);
#pragma unroll
  for (int f4 = 0; f4 < HH / 4; ++f4) {
    float4 hv = hp[f4];
    float hj[4] = {hv.x, hv.y, hv.z, hv.w};
#pragma unroll
    for (int j = 0; j < 4; ++j) {
      int f = f4 * 4 + j;
#pragma unroll
      for (int k = 0; k < KK; ++k)
        logit[k] = fmaf(hj[j], env_w[f * KK + k], logit[k]);
    }
  }
  float m = logit[0];
#pragma unroll
  for (int k = 1; k < KK; ++k) m = fmaxf(m, logit[k]);
  float p[KK];
  float s = 0.f;
#pragma unroll
  for (int k = 0; k < KK; ++k) {
    p[k] = expf(logit[k] - m);
    s += p[k];
  }
#pragma unroll
  for (int k = 0; k < KK; ++k) {
    float pi = p[k] / s;
    e_out[n * KK + k] = ((double)pi > 0.1) ? pi : 0.0f;
  }
}

// ---------------- GCN gather (CSR, no atomics) ----------------

__global__ __launch_bounds__(256) void gather_kernel(const int2* __restrict__ csr,
                                                     const int* __restrict__ offs,
                                                     const int* __restrict__ deg,
                                                     const float* __restrict__ h,
                                                     float* __restrict__ agg) {
  int n = blockIdx.x * 4 + (threadIdx.x >> 6);
  if (n >= NN) return;
  int lane = threadIdx.x & 63;
  int j = offs[n];
  int end = j + deg[n];
  float a0 = 0.f, a1 = 0.f, a2 = 0.f, a3 = 0.f;
  for (; j + 3 < end; j += 4) {
    int2 p0 = csr[j], p1 = csr[j + 1], p2 = csr[j + 2], p3 = csr[j + 3];
    float h0 = h[p0.x * HH + lane];
    float h1 = h[p1.x * HH + lane];
    float h2 = h[p2.x * HH + lane];
    float h3 = h[p3.x * HH + lane];
    a0 = fmaf(h0, __int_as_float(p0.y), a0);
    a1 = fmaf(h1, __int_as_float(p1.y), a1);
    a2 = fmaf(h2, __int_as_float(p2.y), a2);
    a3 = fmaf(h3, __int_as_float(p3.y), a3);
  }
  for (; j < end; ++j) {
    int2 p = csr[j];
    a0 = fmaf(h[p.x * HH + lane], __int_as_float(p.y), a0);
  }
  agg[n * HH + lane] = (a0 + a1) + (a2 + a3);
}

// ---------------- conv: o-sliced, LDS-hi, scalar-pipe weights ----------------
// Structure as round 10 (lane=node, wave owns 8-wide o-slice, weights via
// uniform s_load, hi_s stride 132). SINGLE CHANGE vs round 10: f4 loop is
// `#pragma unroll 4` instead of full unroll. R10 counters showed the full
// unroll let the scheduler prefetch ~32 ds_read_b128 results -> VGPR 128 +
// ~109MB/dispatch scratch spill traffic (WRITE_SIZE 134MB vs 25.6MB ideal),
// occupancy 20%, VALUBusy 22%. Bounding the unroll caps the prefetch window
// (~16 VGPR of hv) -> no spill, higher occupancy. (Bank conflicts measured
// negligible: 2.85M cyc / 256 CU = ~4.6us — not worth a layout change.)

__global__ __launch_bounds__(512) void conv_kernel(float* __restrict__ h,
                                                   const float* __restrict__ agg,
                                                   const float* __restrict__ eg,
                                                   const float* __restrict__ w) {
  __shared__ float hi_s[64 * 132];  // 33.8 KB
  __shared__ float es[64 * 8];      // 2 KB

  int t = threadIdx.x;
  int n0 = blockIdx.x * 64;
  int sn = t >> 3, sc = t & 7;  // staging: node, 16-float chunk

  // stage hi = [agg(0..63) || h(64..127)]; dest f = sc*16
  {
    int n = n0 + sn;
    float* dst = hi_s + sn * 132 + sc * 16;
    if (n < NN) {
      const float* src = (sc < 4) ? (agg + (size_t)n * HH + sc * 16)
                                  : (h + (size_t)n * HH + (sc - 4) * 16);
#pragma unroll
      for (int q = 0; q < 4; ++q)
        reinterpret_cast<float4*>(dst)[q] =
            reinterpret_cast<const float4*>(src)[q];
    } else {
      float4 z = make_float4(0.f, 0.f, 0.f, 0.f);
#pragma unroll
      for (int q = 0; q < 4; ++q) reinterpret_cast<float4*>(dst)[q] = z;
    }
  }
  // stage e (coalesced: thread t -> node t>>3, head t&7)
  {
    int n = n0 + sn;
    es[t] = (n < NN) ? eg[(size_t)n * KK + sc] : 0.f;
  }
  __syncthreads();

  int lane = t & 63;                                      // node within block
  int wvu = __builtin_amdgcn_readfirstlane(t >> 6);       // uniform wave id
  const float* hrow = hi_s + lane * 132;
  const float* wb = w + wvu * 8;  // this wave's o-slice base

  float out[8];
#pragma unroll
  for (int j = 0; j < 8; ++j) out[j] = 0.f;

  for (int k = 0; k < KK; ++k) {
    const float* wk = wb + k * (2 * HH * HH);
    float hacc[8];
#pragma unroll
    for (int j = 0; j < 8; ++j) hacc[j] = 0.f;
#pragma unroll 4
    for (int f4 = 0; f4 < 32; ++f4) {
      float4 hv = *reinterpret_cast<const float4*>(hrow + f4 * 4);
      const float* wf = wk + f4 * 4 * HH;  // uniform -> s_load
#pragma unroll
      for (int j = 0; j < 8; ++j) hacc[j] = fmaf(hv.x, wf[j], hacc[j]);
#pragma unroll
      for (int j = 0; j < 8; ++j) hacc[j] = fmaf(hv.y, wf[HH + j], hacc[j]);
#pragma unroll
      for (int j = 0; j < 8; ++j) hacc[j] = fmaf(hv.z, wf[2 * HH + j], hacc[j]);
#pragma unroll
      for (int j = 0; j < 8; ++j) hacc[j] = fmaf(hv.w, wf[3 * HH + j], hacc[j]);
    }
    float ek = es[lane * 8 + k];
#pragma unroll
    for (int j = 0; j < 8; ++j) out[j] = fmaf(ek, hacc[j], out[j]);
  }

  __syncthreads();  // all waves done reading hi_s
  // res = relu(h + out) into the (now free) agg half of hi_s, for coalescing
#pragma unroll
  for (int j = 0; j < 8; ++j) {
    int o = wvu * 8 + j;
    hi_s[lane * 132 + o] = fmaxf(hrow[64 + o] + out[j], 0.f);
  }
  __syncthreads();
  // coalesced in-place store of this block's 64 rows
  {
    int n = n0 + sn;
    if (n < NN) {
      float* dst = h + (size_t)n * HH + sc * 8;
      const float* srcl = hi_s + sn * 132 + sc * 8;
      reinterpret_cast<float4*>(dst)[0] = reinterpret_cast<const float4*>(srcl)[0];
      reinterpret_cast<float4*>(dst)[1] = reinterpret_cast<const float4*>(srcl)[1];
    }
  }
}

// ---------------- fc1 ----------------

__global__ __launch_bounds__(256) void fc1_kernel(const float* __restrict__ h,
                                                  const float* __restrict__ w,
                                                  const float* __restrict__ b,
                                                  float* __restrict__ out) {
  int id = blockIdx.x * 256 + threadIdx.x;
  int n = id >> 4, c = id & 15;
  const float* hr = h + n * HH;
  float acc = b[c];
#pragma unroll
  for (int o = 0; o < HH; ++o) acc = fmaf(hr[o], w[o * CC + c], acc);
  out[id] = acc;
}

// ---------------- launch ----------------

extern "C" void kernel_launch(void* const* d_in, const int* in_sizes, int n_in,
                              void* d_out, int out_size, void* d_ws, size_t ws_size,
                              hipStream_t stream) {
  const float* x      = (const float*)d_in[0];
  const int*   ei     = (const int*)d_in[1];
  const float* fc0_w  = (const float*)d_in[2];
  const float* fc0_b  = (const float*)d_in[3];
  const float* fc1_w  = (const float*)d_in[4];
  const float* fc1_b  = (const float*)d_in[5];
  const float* env_w  = (const float*)d_in[6];
  const float* env_b  = (const float*)d_in[7];
  const float* conv_w = (const float*)d_in[8];
  float* out = (float*)d_out;

  float* ws   = (float*)d_ws;
  float* h    = ws;                        // 6,400,000
  float* agg  = ws + 6400000;              // 6,400,000
  float* e_g  = ws + 12800000;             // 800,000
  float* dn   = ws + 13600000;             // 100,000
  int*   degi = (int*)(ws + 13700000);     // 100,000
  int*   offs = (int*)(ws + 13800000);     // 100,000
  int*   curs = (int*)(ws + 13900000);     // 100,000
  int*   bsum = (int*)(ws + 14000000);     // 1,024
  int2*  csr  = (int2*)(ws + 14002000);    // 1,600,000 * 8B

  const int* row = ei;
  const int* col = ei + EE;

  hipMemsetAsync(degi, 0, NN * sizeof(int), stream);
  hipMemsetAsync(curs, 0, NN * sizeof(int), stream);
  deg_kernel<<<EE / 256, 256, 0, stream>>>(col, degi);
  dn_kernel<<<NB_SCAN, 256, 0, stream>>>(degi, dn);
  scan1_kernel<<<NB_SCAN, 256, 0, stream>>>(degi, offs, bsum);
  scan2_kernel<<<1, 256, 0, stream>>>(bsum);
  scan3_kernel<<<NB_SCAN, 256, 0, stream>>>(offs, bsum);
  fill_kernel<<<EE / 256, 256, 0, stream>>>(row, col, offs, curs, dn, csr);

  fc0_kernel<<<(NN * HH) / 256, 256, 0, stream>>>(x, fc0_w, fc0_b, h);

  for (int l = 0; l < LL; ++l) {
    env_kernel<<<NB_SCAN, 256, 0, stream>>>(
        h, env_w + l * (2 * HH * KK), env_b + l * KK, e_g);
    gather_kernel<<<(NN + 3) / 4, 256, 0, stream>>>(csr, offs, degi, h, agg);
    conv_kernel<<<(NN + 63) / 64, 512, 0, stream>>>(
        h, agg, e_g, conv_w + l * (KK * 2 * HH * HH));
  }

  fc1_kernel<<<(NN * CC) / 256, 256, 0, stream>>>(h, fc1_w, fc1_b, out);
}